// Round 5
// baseline (155.933 us; speedup 1.0000x reference)
//
#include <hip/hip_runtime.h>

// SimpleSNN: T=16, B=4096, N_IN=784, N_HID=256, N_OUT=10
// gemm1: bf16 MFMA two-term (hi+lo) exact split.
//   Pure global_load_lds staging: A staged as RAW FP32 (no reg round-trip),
//   fp32->bf16 truncate-pack happens at fragment-read time (exact for {0,1}).
//   128x128 tile, 256 thr, BK=32, double-buffered 64KB LDS -> 2 blocks/CU.
//   XOR slot swizzle (source-side) for conflict-free ds_read_b128.
//   Bijective XCD swizzle, y-fast: both n-tiles of an X panel on one XCD.

#define T_STEPS 16
#define B_SZ    4096
#define N_IN    784
#define N_HID   256
#define N_OUT   10
#define M_TOT   (T_STEPS * B_SZ)   // 65536
#define KPAD    800                // 784 padded to 25*32
#define NT      25                 // k-steps

typedef __bf16 bf16x8 __attribute__((ext_vector_type(8)));
typedef float  f32x4  __attribute__((ext_vector_type(4)));
typedef unsigned short ushort_t;
typedef unsigned int   u32;

// ---------------- conv_w: split W1 into hi/lo bf16, pad K to 800 -----------
__device__ __forceinline__ unsigned short bf16_rne(float f) {
    u32 u = __builtin_bit_cast(u32, f);
    u += 0x7fffu + ((u >> 16) & 1u);
    return (unsigned short)(u >> 16);
}

__global__ __launch_bounds__(256) void conv_w(
    const float* __restrict__ W1,
    ushort_t* __restrict__ Whi, ushort_t* __restrict__ Wlo)
{
    const int idx = blockIdx.x * 256 + threadIdx.x;
    if (idx >= N_HID * KPAD) return;
    const int n = idx / KPAD, k = idx % KPAD;
    unsigned short hh = 0, ll = 0;
    if (k < N_IN) {
        const float wv = W1[n * N_IN + k];
        hh = bf16_rne(wv);
        const float hf = __builtin_bit_cast(float, (u32)hh << 16);
        ll = bf16_rne(wv - hf);
    }
    Whi[idx] = hh;
    Wlo[idx] = ll;
}

// ---------------- gemm1 ----------------------------------------------------
__device__ __forceinline__ u32 pack_hi16(u32 a, u32 b) {
    return (a >> 16) | (b & 0xffff0000u);   // bf16 truncation; exact for {0,1}
}

__global__ __launch_bounds__(256, 2) void gemm1_mfma(
    const float* __restrict__ X,
    const ushort_t* __restrict__ Whi,
    const ushort_t* __restrict__ Wlo,
    const float* __restrict__ b1,
    float* __restrict__ C)
{
    // A: [row][16B-slot p], p = u ^ (row&7), u = k-quad (4 fp32).  32 KB
    // B: [row][16B-slot p], p = u ^ (row&3), u = k-octet (8 bf16). 16 KB each
    __shared__ float    Afs[2][128 * 32];
    __shared__ ushort_t Bhs[2][128 * 32];
    __shared__ ushort_t Bls[2][128 * 32];

    const int tid  = threadIdx.x;
    const int lane = tid & 63;
    const int w    = tid >> 6;         // wave 0..3
    const int wm   = w >> 1;
    const int wn   = w & 1;
    // bijective XCD swizzle (1024 blocks, 8 XCDs), y-fast logical order:
    // logical lb = mtile*2 + ntile; XCD gets contiguous chunk of 128 lbs.
    const int bid = blockIdx.x;
    const int lb  = (bid & 7) * 128 + (bid >> 3);
    const int m0  = (lb >> 1) * 128;
    const int n0  = (lb & 1) * 128;
    const int ls  = lane >> 4;         // k-slice 0..3
    const int lr  = lane & 15;

    f32x4 acc[4][4];
    #pragma unroll
    for (int i = 0; i < 4; ++i)
        #pragma unroll
        for (int j = 0; j < 4; ++j)
            #pragma unroll
            for (int q = 0; q < 4; ++q)
                acc[i][j][q] = 0.0f;

    // stage tile (k0 = kt*32) into buffer bi: pure global_load_lds
    auto stage = [&](int bi, int k0, bool clamp) {
        // A: 1024 16B-units; unit = q*256 + tid; row = unit>>3, pu = unit&7
        #pragma unroll
        for (int q = 0; q < 4; ++q) {
            const int unit = q * 256 + tid;
            const int row  = unit >> 3;
            const int u4   = ((unit & 7) ^ (row & 7)) << 2;   // k offset (floats)
            const int kk   = (clamp && (k0 + u4 >= N_IN)) ? 0 : (k0 + u4);
            const float* src = X + (size_t)(m0 + row) * N_IN + kk;
            float* dst = &Afs[bi][(q * 256 + (w << 6)) * 4];  // wave-uniform base
            __builtin_amdgcn_global_load_lds(
                (const __attribute__((address_space(1))) void*)src,
                (__attribute__((address_space(3))) void*)dst, 16, 0, 0);
        }
        // B: 512 16B-units each; unit = q*256 + tid; row = unit>>2, pu = unit&3
        #pragma unroll
        for (int q = 0; q < 2; ++q) {
            const int unit = q * 256 + tid;
            const int row  = unit >> 2;
            const int u8   = ((unit & 3) ^ (row & 3)) << 3;   // k offset (ushorts)
            const size_t so = (size_t)(n0 + row) * KPAD + k0 + u8;
            ushort_t* dh = &Bhs[bi][(q * 256 + (w << 6)) * 8];
            ushort_t* dl = &Bls[bi][(q * 256 + (w << 6)) * 8];
            __builtin_amdgcn_global_load_lds(
                (const __attribute__((address_space(1))) void*)(Whi + so),
                (__attribute__((address_space(3))) void*)dh, 16, 0, 0);
            __builtin_amdgcn_global_load_lds(
                (const __attribute__((address_space(1))) void*)(Wlo + so),
                (__attribute__((address_space(3))) void*)dl, 16, 0, 0);
        }
    };

    // fragment LDS offsets (invariant; buf selects the array half)
    int aOff0[4], aOff1[4], bOff[4];
    #pragma unroll
    for (int i = 0; i < 4; ++i) {
        const int R = wm * 64 + i * 16 + lr;
        aOff0[i] = R * 32 + ((((2 * ls)     ^ (R & 7))) << 2);
        aOff1[i] = R * 32 + ((((2 * ls + 1) ^ (R & 7))) << 2);
    }
    #pragma unroll
    for (int j = 0; j < 4; ++j) {
        const int R = wn * 64 + j * 16 + lr;
        bOff[j] = R * 32 + ((ls ^ (R & 3)) << 3);
    }

    stage(0, 0, false);

    int buf = 0;
    for (int kt = 0; kt < NT; ++kt) {
        __syncthreads();               // buf staged (issued a full k-step ago)

        if (kt + 1 < NT)
            stage(buf ^ 1, (kt + 1) * 32, kt + 1 == NT - 1);

        // A frags: ds_read fp32 pairs, truncate-pack to bf16 (exact for {0,1})
        bf16x8 af[4];
        #pragma unroll
        for (int i = 0; i < 4; ++i) {
            const float4 fa = *reinterpret_cast<const float4*>(&Afs[buf][aOff0[i]]);
            const float4 fb = *reinterpret_cast<const float4*>(&Afs[buf][aOff1[i]]);
            uint4 pk;
            pk.x = pack_hi16(__builtin_bit_cast(u32, fa.x), __builtin_bit_cast(u32, fa.y));
            pk.y = pack_hi16(__builtin_bit_cast(u32, fa.z), __builtin_bit_cast(u32, fa.w));
            pk.z = pack_hi16(__builtin_bit_cast(u32, fb.x), __builtin_bit_cast(u32, fb.y));
            pk.w = pack_hi16(__builtin_bit_cast(u32, fb.z), __builtin_bit_cast(u32, fb.w));
            af[i] = __builtin_bit_cast(bf16x8, pk);
        }
        bf16x8 bh[4], bl[4];
        #pragma unroll
        for (int j = 0; j < 4; ++j) {
            bh[j] = *reinterpret_cast<const bf16x8*>(&Bhs[buf][bOff[j]]);
            bl[j] = *reinterpret_cast<const bf16x8*>(&Bls[buf][bOff[j]]);
        }

        // hi pass then lo pass: per-acc order identical to verified rounds
        #pragma unroll
        for (int i = 0; i < 4; ++i)
            #pragma unroll
            for (int j = 0; j < 4; ++j)
                acc[i][j] = __builtin_amdgcn_mfma_f32_16x16x32_bf16(
                    af[i], bh[j], acc[i][j], 0, 0, 0);
        #pragma unroll
        for (int i = 0; i < 4; ++i)
            #pragma unroll
            for (int j = 0; j < 4; ++j)
                acc[i][j] = __builtin_amdgcn_mfma_f32_16x16x32_bf16(
                    af[i], bl[j], acc[i][j], 0, 0, 0);

        buf ^= 1;
    }

    // epilogue: C/D layout col=lane&15, row=(lane>>4)*4+q (m89-verified)
    #pragma unroll
    for (int j = 0; j < 4; ++j) {
        const int col  = n0 + wn * 64 + j * 16 + lr;
        const float bb = b1[col];
        #pragma unroll
        for (int i = 0; i < 4; ++i) {
            const int rbase = m0 + wm * 64 + i * 16 + (ls << 2);
            #pragma unroll
            for (int q = 0; q < 4; ++q)
                C[(size_t)(rbase + q) * N_HID + col] = acc[i][j][q] + bb;
        }
    }
}

// ---------------- LIF1: per (b,n), loop t; overwrite C1 with z1 ------------
__global__ __launch_bounds__(256) void lif1_kernel(float* __restrict__ C1)
{
    const int g = blockIdx.x * 256 + threadIdx.x;
    const size_t stride = (size_t)B_SZ * N_HID;
    float v = 0.0f, cur = 0.0f;
    #pragma unroll
    for (int t = 0; t < T_STEPS; ++t) {
        const size_t off = (size_t)t * stride + g;
        const float c = C1[off];
        const float vd = v + 0.1f * ((0.0f - v) + cur);
        const float id = cur - 0.2f * cur;
        const bool  sp = vd > 1.0f;
        C1[off] = sp ? 1.0f : 0.0f;
        v = sp ? 0.0f : vd;
        cur = id + c;
    }
}

// ---------------- GEMM2: M=65536, K=256, N=10; 64 rows/block, 640 thr ------
__global__ __launch_bounds__(640) void gemm2_f32(
    const float* __restrict__ Z, const float* __restrict__ W2,
    const float* __restrict__ b2, float* __restrict__ C2)
{
    __shared__ float zs[64 * 268];
    __shared__ float ws[N_OUT * N_HID];
    const int tid = threadIdx.x;
    const int m0 = blockIdx.x * 64;

    for (int idx = tid; idx < 4096; idx += 640) {
        const int r = idx >> 6;
        const int c = (idx & 63) << 2;
        *(float4*)&zs[r * 268 + c] =
            *(const float4*)&Z[(size_t)(m0 + r) * N_HID + c];
    }
    *(float4*)&ws[tid * 4] = *(const float4*)&W2[tid * 4];
    __syncthreads();

    const int o = tid >> 6;
    const int r = tid & 63;
    float acc = b2[o];
    #pragma unroll
    for (int k = 0; k < N_HID; k += 4) {
        const float4 z4 = *(const float4*)&zs[r * 268 + k];
        const float4 w4 = *(const float4*)&ws[o * N_HID + k];
        acc += z4.x * w4.x + z4.y * w4.y + z4.z * w4.z + z4.w * w4.w;
    }
    C2[(size_t)(m0 + r) * N_OUT + o] = acc;
}

// ---------------- LIF2: per (b,o), loop t; accumulate spike count ----------
__global__ __launch_bounds__(256) void lif2_kernel(
    const float* __restrict__ C2, float* __restrict__ out)
{
    const int g = blockIdx.x * 256 + threadIdx.x;
    const int stride = B_SZ * N_OUT;
    float v = 0.0f, cur = 0.0f, s = 0.0f;
    #pragma unroll
    for (int t = 0; t < T_STEPS; ++t) {
        const float c = C2[t * stride + g];
        const float vd = v + 0.1f * ((0.0f - v) + cur);
        const float id = cur - 0.2f * cur;
        const bool  sp = vd > 1.0f;
        s += sp ? 1.0f : 0.0f;
        v = sp ? 0.0f : vd;
        cur = id + c;
    }
    out[g] = s;
}

extern "C" void kernel_launch(void* const* d_in, const int* in_sizes, int n_in,
                              void* d_out, int out_size, void* d_ws, size_t ws_size,
                              hipStream_t stream)
{
    const float* X  = (const float*)d_in[0];
    const float* W1 = (const float*)d_in[1];
    const float* b1 = (const float*)d_in[2];
    const float* W2 = (const float*)d_in[3];
    const float* b2 = (const float*)d_in[4];
    float* out = (float*)d_out;

    ushort_t* Whi = (ushort_t*)d_ws;                       // 256*800 bf16
    ushort_t* Wlo = Whi + N_HID * KPAD;                    // 256*800 bf16
    float* C1 = (float*)((char*)d_ws + (1 << 20));         // 65536x256 fp32
    float* C2 = C1 + (size_t)M_TOT * N_HID;                // 65536x10 fp32

    conv_w<<<(N_HID * KPAD + 255) / 256, 256, 0, stream>>>(W1, Whi, Wlo);

    gemm1_mfma<<<M_TOT / 128 * (N_HID / 128), 256, 0, stream>>>(X, Whi, Wlo, b1, C1);

    lif1_kernel<<<(B_SZ * N_HID) / 256, 256, 0, stream>>>(C1);

    gemm2_f32<<<M_TOT / 64, 640, 0, stream>>>(C1, W2, b2, C2);

    lif2_kernel<<<(B_SZ * N_OUT) / 256, 256, 0, stream>>>(C2, out);
}

// Round 6
// 151.359 us; speedup vs baseline: 1.0302x; 1.0302x over previous
//
#include <hip/hip_runtime.h>

// SimpleSNN: T=16, B=4096, N_IN=784, N_HID=256, N_OUT=10
// gemm1: bf16 MFMA two-term (hi+lo) exact split; counted-vmcnt pipeline
//   (T3+T4+T5): raw s_barrier, s_waitcnt vmcnt(6) (never drains to 0),
//   tile 128x256 (full N), 8 waves, double-buffered 96KB LDS, A staged as
//   raw fp32 via global_load_lds (pack to bf16 at fragment-read; exact
//   for {0,1}); B = pre-split W1 hi/lo bf16 (L2-resident).

#define T_STEPS 16
#define B_SZ    4096
#define N_IN    784
#define N_HID   256
#define N_OUT   10
#define M_TOT   (T_STEPS * B_SZ)   // 65536
#define KPAD    800                // 784 padded to 25*32
#define NT      25                 // k-steps

typedef __bf16 bf16x8 __attribute__((ext_vector_type(8)));
typedef float  f32x4  __attribute__((ext_vector_type(4)));
typedef unsigned short ushort_t;
typedef unsigned int   u32;

#define GLOAD_LDS(SRC, DST) \
    __builtin_amdgcn_global_load_lds( \
        (const __attribute__((address_space(1))) void*)(SRC), \
        (__attribute__((address_space(3))) void*)(DST), 16, 0, 0)

// ---------------- conv_w: split W1 into hi/lo bf16, pad K to 800 -----------
__device__ __forceinline__ unsigned short bf16_rne(float f) {
    u32 u = __builtin_bit_cast(u32, f);
    u += 0x7fffu + ((u >> 16) & 1u);
    return (unsigned short)(u >> 16);
}

__global__ __launch_bounds__(256) void conv_w(
    const float* __restrict__ W1,
    ushort_t* __restrict__ Whi, ushort_t* __restrict__ Wlo)
{
    const int idx = blockIdx.x * 256 + threadIdx.x;
    if (idx >= N_HID * KPAD) return;
    const int n = idx / KPAD, k = idx % KPAD;
    unsigned short hh = 0, ll = 0;
    if (k < N_IN) {
        const float wv = W1[n * N_IN + k];
        hh = bf16_rne(wv);
        const float hf = __builtin_bit_cast(float, (u32)hh << 16);
        ll = bf16_rne(wv - hf);
    }
    Whi[idx] = hh;
    Wlo[idx] = ll;
}

// ---------------- gemm1 ----------------------------------------------------
__device__ __forceinline__ u32 pack_hi16(u32 a, u32 b) {
    return (a >> 16) | (b & 0xffff0000u);   // bf16 truncation; exact for {0,1}
}

__global__ __launch_bounds__(512, 2) void gemm1_mfma(
    const float* __restrict__ X,
    const ushort_t* __restrict__ Whi,
    const ushort_t* __restrict__ Wlo,
    const float* __restrict__ b1,
    float* __restrict__ C)
{
    // A: [128 rows][8 slots of 16B]; phys slot p holds source k-quad p^(row&7)
    // B: [256 rows][4 slots of 16B]; phys slot p holds source k-octet p^((row>>1)&3)
    __shared__ float    Afs[2][128 * 32];   // 2 x 16 KB
    __shared__ ushort_t Bhs[2][256 * 32];   // 2 x 16 KB
    __shared__ ushort_t Bls[2][256 * 32];   // 2 x 16 KB

    const int tid  = threadIdx.x;
    const int lane = tid & 63;
    const int w    = tid >> 6;         // wave 0..7
    const int wm   = w >> 2;           // m 64-subtile (0..1)
    const int wn   = w & 3;            // n 64-subtile (0..3)
    const int m0   = blockIdx.x * 128;
    const int ls   = lane >> 4;        // k-slice 0..3
    const int lr   = lane & 15;

    f32x4 acc[4][4];
    #pragma unroll
    for (int i = 0; i < 4; ++i)
        #pragma unroll
        for (int j = 0; j < 4; ++j)
            #pragma unroll
            for (int q = 0; q < 4; ++q)
                acc[i][j][q] = 0.0f;

    // 6 global_load_lds per thread per tile (2 A + 2 Bh + 2 Bl)
    auto stage = [&](int bi, int k0) {
        #pragma unroll
        for (int q = 0; q < 2; ++q) {          // A: 1024 16B-units
            const int u   = q * 512 + tid;
            const int row = u >> 3;
            const int ks  = ((u & 7) ^ (row & 7)) << 2;     // float offset
            const int kk  = (k0 + ks < N_IN) ? (k0 + ks) : 0;  // tail clamp (B=0 there)
            GLOAD_LDS(X + (size_t)(m0 + row) * N_IN + kk, &Afs[bi][u * 4]);
        }
        #pragma unroll
        for (int q = 0; q < 2; ++q) {          // B: 1024 16B-units each
            const int u   = q * 512 + tid;
            const int row = u >> 2;
            const int sl  = ((u & 3) ^ ((row >> 1) & 3)) << 3;  // ushort offset
            const size_t so = (size_t)row * KPAD + k0 + sl;
            GLOAD_LDS(Whi + so, &Bhs[bi][u * 8]);
            GLOAD_LDS(Wlo + so, &Bls[bi][u * 8]);
        }
    };

    // fragment LDS offsets
    int aOff0[4], aOff1[4], bOff[4];
    #pragma unroll
    for (int i = 0; i < 4; ++i) {
        const int R = wm * 64 + i * 16 + lr;
        aOff0[i] = R * 32 + ((((2 * ls)     ^ (R & 7))) << 2);
        aOff1[i] = R * 32 + ((((2 * ls + 1) ^ (R & 7))) << 2);
    }
    #pragma unroll
    for (int j = 0; j < 4; ++j) {
        const int R = wn * 64 + j * 16 + lr;
        bOff[j] = R * 32 + ((ls ^ ((R >> 1) & 3)) << 3);
    }

    // prologue: tiles 0 and 1 in flight (12 outstanding per thread)
    stage(0, 0);
    stage(1, 32);

    for (int kt = 0; kt < NT; ++kt) {
        const int buf = kt & 1;

        // retire tile kt (oldest 6), keep tile kt+1's 6 in flight
        asm volatile("s_waitcnt vmcnt(6)" ::: "memory");
        __builtin_amdgcn_sched_barrier(0);
        __builtin_amdgcn_s_barrier();              // bar1: buf fully staged
        __builtin_amdgcn_sched_barrier(0);

        bf16x8 af[4], bh[4], bl[4];
        #pragma unroll
        for (int i = 0; i < 4; ++i) {
            const float4 fa = *reinterpret_cast<const float4*>(&Afs[buf][aOff0[i]]);
            const float4 fb = *reinterpret_cast<const float4*>(&Afs[buf][aOff1[i]]);
            uint4 pk;
            pk.x = pack_hi16(__builtin_bit_cast(u32, fa.x), __builtin_bit_cast(u32, fa.y));
            pk.y = pack_hi16(__builtin_bit_cast(u32, fa.z), __builtin_bit_cast(u32, fa.w));
            pk.z = pack_hi16(__builtin_bit_cast(u32, fb.x), __builtin_bit_cast(u32, fb.y));
            pk.w = pack_hi16(__builtin_bit_cast(u32, fb.z), __builtin_bit_cast(u32, fb.w));
            af[i] = __builtin_bit_cast(bf16x8, pk);
        }
        #pragma unroll
        for (int j = 0; j < 4; ++j) {
            bh[j] = *reinterpret_cast<const bf16x8*>(&Bhs[buf][bOff[j]]);
            bl[j] = *reinterpret_cast<const bf16x8*>(&Bls[buf][bOff[j]]);
        }

        asm volatile("s_waitcnt lgkmcnt(0)" ::: "memory");  // my reads in regs
        __builtin_amdgcn_sched_barrier(0);
        __builtin_amdgcn_s_barrier();              // bar2: buf free to overwrite
        __builtin_amdgcn_sched_barrier(0);

        // stage tile kt+2 into this buf (dummy in-bounds re-stage past the end)
        stage(buf, (kt + 2 < NT) ? (kt + 2) * 32 : 0);

        // hi pass then lo pass: per-acc order identical to verified rounds
        __builtin_amdgcn_s_setprio(1);
        #pragma unroll
        for (int i = 0; i < 4; ++i)
            #pragma unroll
            for (int j = 0; j < 4; ++j)
                acc[i][j] = __builtin_amdgcn_mfma_f32_16x16x32_bf16(
                    af[i], bh[j], acc[i][j], 0, 0, 0);
        #pragma unroll
        for (int i = 0; i < 4; ++i)
            #pragma unroll
            for (int j = 0; j < 4; ++j)
                acc[i][j] = __builtin_amdgcn_mfma_f32_16x16x32_bf16(
                    af[i], bl[j], acc[i][j], 0, 0, 0);
        __builtin_amdgcn_s_setprio(0);
    }

    // epilogue: C/D layout col=lane&15, row=(lane>>4)*4+q (m89-verified)
    #pragma unroll
    for (int j = 0; j < 4; ++j) {
        const int col  = wn * 64 + j * 16 + lr;
        const float bb = b1[col];
        #pragma unroll
        for (int i = 0; i < 4; ++i) {
            const int rbase = m0 + wm * 64 + i * 16 + (ls << 2);
            #pragma unroll
            for (int q = 0; q < 4; ++q)
                C[(size_t)(rbase + q) * N_HID + col] = acc[i][j][q] + bb;
        }
    }
}

// ---------------- LIF1: per (b,n), loop t; overwrite C1 with z1 ------------
__global__ __launch_bounds__(256) void lif1_kernel(float* __restrict__ C1)
{
    const int g = blockIdx.x * 256 + threadIdx.x;
    const size_t stride = (size_t)B_SZ * N_HID;
    float v = 0.0f, cur = 0.0f;
    #pragma unroll
    for (int t = 0; t < T_STEPS; ++t) {
        const size_t off = (size_t)t * stride + g;
        const float c = C1[off];
        const float vd = v + 0.1f * ((0.0f - v) + cur);
        const float id = cur - 0.2f * cur;
        const bool  sp = vd > 1.0f;
        C1[off] = sp ? 1.0f : 0.0f;
        v = sp ? 0.0f : vd;
        cur = id + c;
    }
}

// ---------------- GEMM2: M=65536, K=256, N=10; 64 rows/block, 640 thr ------
__global__ __launch_bounds__(640) void gemm2_f32(
    const float* __restrict__ Z, const float* __restrict__ W2,
    const float* __restrict__ b2, float* __restrict__ C2)
{
    __shared__ float zs[64 * 268];
    __shared__ float ws[N_OUT * N_HID];
    const int tid = threadIdx.x;
    const int m0 = blockIdx.x * 64;

    for (int idx = tid; idx < 4096; idx += 640) {
        const int r = idx >> 6;
        const int c = (idx & 63) << 2;
        *(float4*)&zs[r * 268 + c] =
            *(const float4*)&Z[(size_t)(m0 + r) * N_HID + c];
    }
    *(float4*)&ws[tid * 4] = *(const float4*)&W2[tid * 4];
    __syncthreads();

    const int o = tid >> 6;
    const int r = tid & 63;
    float acc = b2[o];
    #pragma unroll
    for (int k = 0; k < N_HID; k += 4) {
        const float4 z4 = *(const float4*)&zs[r * 268 + k];
        const float4 w4 = *(const float4*)&ws[o * N_HID + k];
        acc += z4.x * w4.x + z4.y * w4.y + z4.z * w4.z + z4.w * w4.w;
    }
    C2[(size_t)(m0 + r) * N_OUT + o] = acc;
}

// ---------------- LIF2: per (b,o), loop t; accumulate spike count ----------
__global__ __launch_bounds__(256) void lif2_kernel(
    const float* __restrict__ C2, float* __restrict__ out)
{
    const int g = blockIdx.x * 256 + threadIdx.x;
    const int stride = B_SZ * N_OUT;
    float v = 0.0f, cur = 0.0f, s = 0.0f;
    #pragma unroll
    for (int t = 0; t < T_STEPS; ++t) {
        const float c = C2[t * stride + g];
        const float vd = v + 0.1f * ((0.0f - v) + cur);
        const float id = cur - 0.2f * cur;
        const bool  sp = vd > 1.0f;
        s += sp ? 1.0f : 0.0f;
        v = sp ? 0.0f : vd;
        cur = id + c;
    }
    out[g] = s;
}

extern "C" void kernel_launch(void* const* d_in, const int* in_sizes, int n_in,
                              void* d_out, int out_size, void* d_ws, size_t ws_size,
                              hipStream_t stream)
{
    const float* X  = (const float*)d_in[0];
    const float* W1 = (const float*)d_in[1];
    const float* b1 = (const float*)d_in[2];
    const float* W2 = (const float*)d_in[3];
    const float* b2 = (const float*)d_in[4];
    float* out = (float*)d_out;

    ushort_t* Whi = (ushort_t*)d_ws;                       // 256*800 bf16
    ushort_t* Wlo = Whi + N_HID * KPAD;                    // 256*800 bf16
    float* C1 = (float*)((char*)d_ws + (1 << 20));         // 65536x256 fp32
    float* C2 = C1 + (size_t)M_TOT * N_HID;                // 65536x10 fp32

    conv_w<<<(N_HID * KPAD + 255) / 256, 256, 0, stream>>>(W1, Whi, Wlo);

    gemm1_mfma<<<M_TOT / 128, 512, 0, stream>>>(X, Whi, Wlo, b1, C1);

    lif1_kernel<<<(B_SZ * N_HID) / 256, 256, 0, stream>>>(C1);

    gemm2_f32<<<M_TOT / 64, 640, 0, stream>>>(C1, W2, b2, C2);

    lif2_kernel<<<(B_SZ * N_OUT) / 256, 256, 0, stream>>>(C2, out);
}

// Round 7
// 139.939 us; speedup vs baseline: 1.1143x; 1.0816x over previous
//
#include <hip/hip_runtime.h>

// SimpleSNN: T=16, B=4096, N_IN=784, N_HID=256, N_OUT=10
// gemm1: bf16 MFMA two-term (hi+lo) exact split, m97-verbatim structure:
//   128x128 tile, 256 thr (4 waves), BK=32, SINGLE-buffered 32KB LDS
//   (A raw fp32 + Bh + Bl), plain __syncthreads, 3 blocks/CU -> cross-block
//   overlap covers the barrier drains (m97/m114 mechanism).
//   A packs fp32->bf16 at fragment-read (exact for {0,1}).

#define T_STEPS 16
#define B_SZ    4096
#define N_IN    784
#define N_HID   256
#define N_OUT   10
#define M_TOT   (T_STEPS * B_SZ)   // 65536
#define KPAD    800                // 784 padded to 25*32
#define NT      25                 // k-steps

typedef __bf16 bf16x8 __attribute__((ext_vector_type(8)));
typedef float  f32x4  __attribute__((ext_vector_type(4)));
typedef unsigned short ushort_t;
typedef unsigned int   u32;

#define GLOAD_LDS(SRC, DST) \
    __builtin_amdgcn_global_load_lds( \
        (const __attribute__((address_space(1))) void*)(SRC), \
        (__attribute__((address_space(3))) void*)(DST), 16, 0, 0)

// ---------------- conv_w: split W1 into hi/lo bf16, pad K to 800 -----------
__device__ __forceinline__ unsigned short bf16_rne(float f) {
    u32 u = __builtin_bit_cast(u32, f);
    u += 0x7fffu + ((u >> 16) & 1u);
    return (unsigned short)(u >> 16);
}

__global__ __launch_bounds__(256) void conv_w(
    const float* __restrict__ W1,
    ushort_t* __restrict__ Whi, ushort_t* __restrict__ Wlo)
{
    const int idx = blockIdx.x * 256 + threadIdx.x;
    if (idx >= N_HID * KPAD) return;
    const int n = idx / KPAD, k = idx % KPAD;
    unsigned short hh = 0, ll = 0;
    if (k < N_IN) {
        const float wv = W1[n * N_IN + k];
        hh = bf16_rne(wv);
        const float hf = __builtin_bit_cast(float, (u32)hh << 16);
        ll = bf16_rne(wv - hf);
    }
    Whi[idx] = hh;
    Wlo[idx] = ll;
}

// ---------------- gemm1 ----------------------------------------------------
__device__ __forceinline__ u32 pack_hi16(u32 a, u32 b) {
    return (a >> 16) | (b & 0xffff0000u);   // bf16 truncation; exact for {0,1}
}

__global__ __launch_bounds__(256, 3) void gemm1_mfma(
    const float* __restrict__ X,
    const ushort_t* __restrict__ Whi,
    const ushort_t* __restrict__ Wlo,
    const float* __restrict__ b1,
    float* __restrict__ C)
{
    // A: [128 rows][8 slots of 16B]; phys slot p holds source k-quad p^(row&7)
    // B: [128 rows][4 slots of 16B]; phys slot p holds source k-octet p^((row>>1)&3)
    __shared__ float    Afs[128 * 32];   // 16 KB
    __shared__ ushort_t Bhs[128 * 32];   // 8 KB
    __shared__ ushort_t Bls[128 * 32];   // 8 KB

    const int tid  = threadIdx.x;
    const int lane = tid & 63;
    const int w    = tid >> 6;         // wave 0..3
    const int wm   = w >> 1;           // m 64-subtile
    const int wn   = w & 1;            // n 64-subtile
    // bijective XCD swizzle (1024 blocks, 8 XCDs), y-fast logical order:
    // logical lb = mtile*2 + ntile; each XCD gets a contiguous chunk of 128.
    const int bid = blockIdx.x;
    const int lb  = (bid & 7) * 128 + (bid >> 3);
    const int m0  = (lb >> 1) * 128;
    const int n0  = (lb & 1) * 128;
    const int ls  = lane >> 4;         // k-slice 0..3
    const int lr  = lane & 15;

    f32x4 acc[4][4];
    #pragma unroll
    for (int i = 0; i < 4; ++i)
        #pragma unroll
        for (int j = 0; j < 4; ++j)
            #pragma unroll
            for (int q = 0; q < 4; ++q)
                acc[i][j][q] = 0.0f;

    // 8 global_load_lds per thread per tile (4 A + 2 Bh + 2 Bl)
    auto stage = [&](int k0) {
        #pragma unroll
        for (int q = 0; q < 4; ++q) {          // A: 1024 16B-units
            const int u   = q * 256 + tid;
            const int row = u >> 3;
            const int ks  = ((u & 7) ^ (row & 7)) << 2;        // float offset
            const int kk  = (k0 + ks < N_IN) ? (k0 + ks) : 0;  // tail clamp (B=0 there)
            GLOAD_LDS(X + (size_t)(m0 + row) * N_IN + kk, &Afs[u * 4]);
        }
        #pragma unroll
        for (int q = 0; q < 2; ++q) {          // B: 512 16B-units each
            const int u   = q * 256 + tid;
            const int row = u >> 2;
            const int sl  = ((u & 3) ^ ((row >> 1) & 3)) << 3; // ushort offset
            const size_t so = (size_t)(n0 + row) * KPAD + k0 + sl;
            GLOAD_LDS(Whi + so, &Bhs[u * 8]);
            GLOAD_LDS(Wlo + so, &Bls[u * 8]);
        }
    };

    // fragment LDS offsets (element indices)
    int aOff0[4], aOff1[4], bOff[4];
    #pragma unroll
    for (int i = 0; i < 4; ++i) {
        const int R = wm * 64 + i * 16 + lr;
        aOff0[i] = R * 32 + ((((2 * ls)     ^ (R & 7))) << 2);
        aOff1[i] = R * 32 + ((((2 * ls + 1) ^ (R & 7))) << 2);
    }
    #pragma unroll
    for (int j = 0; j < 4; ++j) {
        const int R = wn * 64 + j * 16 + lr;
        bOff[j] = R * 32 + ((ls ^ ((R >> 1) & 3)) << 3);
    }

    stage(0);

    for (int kt = 0; kt < NT; ++kt) {
        __syncthreads();               // staging of tile kt complete (all waves)

        bf16x8 af[4], bh[4], bl[4];
        #pragma unroll
        for (int i = 0; i < 4; ++i) {
            const float4 fa = *reinterpret_cast<const float4*>(&Afs[aOff0[i]]);
            const float4 fb = *reinterpret_cast<const float4*>(&Afs[aOff1[i]]);
            uint4 pk;
            pk.x = pack_hi16(__builtin_bit_cast(u32, fa.x), __builtin_bit_cast(u32, fa.y));
            pk.y = pack_hi16(__builtin_bit_cast(u32, fa.z), __builtin_bit_cast(u32, fa.w));
            pk.z = pack_hi16(__builtin_bit_cast(u32, fb.x), __builtin_bit_cast(u32, fb.y));
            pk.w = pack_hi16(__builtin_bit_cast(u32, fb.z), __builtin_bit_cast(u32, fb.w));
            af[i] = __builtin_bit_cast(bf16x8, pk);
        }
        #pragma unroll
        for (int j = 0; j < 4; ++j) {
            bh[j] = *reinterpret_cast<const bf16x8*>(&Bhs[bOff[j]]);
            bl[j] = *reinterpret_cast<const bf16x8*>(&Bls[bOff[j]]);
        }

        __syncthreads();               // all waves' reads done; buffer free

        if (kt + 1 < NT) stage((kt + 1) * 32);   // issue next tile's loads

        // hi pass then lo pass: per-acc order identical to verified rounds
        #pragma unroll
        for (int i = 0; i < 4; ++i)
            #pragma unroll
            for (int j = 0; j < 4; ++j)
                acc[i][j] = __builtin_amdgcn_mfma_f32_16x16x32_bf16(
                    af[i], bh[j], acc[i][j], 0, 0, 0);
        #pragma unroll
        for (int i = 0; i < 4; ++i)
            #pragma unroll
            for (int j = 0; j < 4; ++j)
                acc[i][j] = __builtin_amdgcn_mfma_f32_16x16x32_bf16(
                    af[i], bl[j], acc[i][j], 0, 0, 0);
    }

    // epilogue: C/D layout col=lane&15, row=(lane>>4)*4+q (m89-verified)
    #pragma unroll
    for (int j = 0; j < 4; ++j) {
        const int col  = n0 + wn * 64 + j * 16 + lr;
        const float bb = b1[col];
        #pragma unroll
        for (int i = 0; i < 4; ++i) {
            const int rbase = m0 + wm * 64 + i * 16 + (ls << 2);
            #pragma unroll
            for (int q = 0; q < 4; ++q)
                C[(size_t)(rbase + q) * N_HID + col] = acc[i][j][q] + bb;
        }
    }
}

// ---------------- LIF1: per (b,n), loop t; overwrite C1 with z1 ------------
__global__ __launch_bounds__(256) void lif1_kernel(float* __restrict__ C1)
{
    const int g = blockIdx.x * 256 + threadIdx.x;
    const size_t stride = (size_t)B_SZ * N_HID;
    float v = 0.0f, cur = 0.0f;
    #pragma unroll
    for (int t = 0; t < T_STEPS; ++t) {
        const size_t off = (size_t)t * stride + g;
        const float c = C1[off];
        const float vd = v + 0.1f * ((0.0f - v) + cur);
        const float id = cur - 0.2f * cur;
        const bool  sp = vd > 1.0f;
        C1[off] = sp ? 1.0f : 0.0f;
        v = sp ? 0.0f : vd;
        cur = id + c;
    }
}

// ---------------- GEMM2: M=65536, K=256, N=10; 64 rows/block, 640 thr ------
__global__ __launch_bounds__(640) void gemm2_f32(
    const float* __restrict__ Z, const float* __restrict__ W2,
    const float* __restrict__ b2, float* __restrict__ C2)
{
    __shared__ float zs[64 * 268];
    __shared__ float ws[N_OUT * N_HID];
    const int tid = threadIdx.x;
    const int m0 = blockIdx.x * 64;

    for (int idx = tid; idx < 4096; idx += 640) {
        const int r = idx >> 6;
        const int c = (idx & 63) << 2;
        *(float4*)&zs[r * 268 + c] =
            *(const float4*)&Z[(size_t)(m0 + r) * N_HID + c];
    }
    *(float4*)&ws[tid * 4] = *(const float4*)&W2[tid * 4];
    __syncthreads();

    const int o = tid >> 6;
    const int r = tid & 63;
    float acc = b2[o];
    #pragma unroll
    for (int k = 0; k < N_HID; k += 4) {
        const float4 z4 = *(const float4*)&zs[r * 268 + k];
        const float4 w4 = *(const float4*)&ws[o * N_HID + k];
        acc += z4.x * w4.x + z4.y * w4.y + z4.z * w4.z + z4.w * w4.w;
    }
    C2[(size_t)(m0 + r) * N_OUT + o] = acc;
}

// ---------------- LIF2: per (b,o), loop t; accumulate spike count ----------
__global__ __launch_bounds__(256) void lif2_kernel(
    const float* __restrict__ C2, float* __restrict__ out)
{
    const int g = blockIdx.x * 256 + threadIdx.x;
    const int stride = B_SZ * N_OUT;
    float v = 0.0f, cur = 0.0f, s = 0.0f;
    #pragma unroll
    for (int t = 0; t < T_STEPS; ++t) {
        const float c = C2[t * stride + g];
        const float vd = v + 0.1f * ((0.0f - v) + cur);
        const float id = cur - 0.2f * cur;
        const bool  sp = vd > 1.0f;
        s += sp ? 1.0f : 0.0f;
        v = sp ? 0.0f : vd;
        cur = id + c;
    }
    out[g] = s;
}

extern "C" void kernel_launch(void* const* d_in, const int* in_sizes, int n_in,
                              void* d_out, int out_size, void* d_ws, size_t ws_size,
                              hipStream_t stream)
{
    const float* X  = (const float*)d_in[0];
    const float* W1 = (const float*)d_in[1];
    const float* b1 = (const float*)d_in[2];
    const float* W2 = (const float*)d_in[3];
    const float* b2 = (const float*)d_in[4];
    float* out = (float*)d_out;

    ushort_t* Whi = (ushort_t*)d_ws;                       // 256*800 bf16
    ushort_t* Wlo = Whi + N_HID * KPAD;                    // 256*800 bf16
    float* C1 = (float*)((char*)d_ws + (1 << 20));         // 65536x256 fp32
    float* C2 = C1 + (size_t)M_TOT * N_HID;                // 65536x10 fp32

    conv_w<<<(N_HID * KPAD + 255) / 256, 256, 0, stream>>>(W1, Whi, Wlo);

    gemm1_mfma<<<M_TOT / 128 * (N_HID / 128), 256, 0, stream>>>(X, Whi, Wlo, b1, C1);

    lif1_kernel<<<(B_SZ * N_HID) / 256, 256, 0, stream>>>(C1);

    gemm2_f32<<<M_TOT / 64, 640, 0, stream>>>(C1, W2, b2, C2);

    lif2_kernel<<<(B_SZ * N_OUT) / 256, 256, 0, stream>>>(C2, out);
}